// Round 8
// baseline (36.247 us; speedup 1.0000x reference)
//
#include <hip/hip_runtime.h>

#define T_DIM 1024
#define B_DIM 32
#define C_DIM 512

typedef float f32x4 __attribute__((ext_vector_type(4)));

// Kernel 1: one block per batch. Label scan -> compaction -> means of labeled
// rows -> wave-parallel prefix products -> scale_s[p*B+b] for all p.
__global__ __launch_bounds__(256) void k_scale(const float* __restrict__ video,
                                               const int* __restrict__ labels,
                                               float* __restrict__ scale_s) {
    int b    = blockIdx.x;
    int tid  = threadIdx.x;
    int lane = tid & 63;
    int wave = tid >> 6;
    __shared__ float vm[T_DIM];
    __shared__ int   pos[T_DIM];
    __shared__ int   waveTot[4];
    __shared__ float pre[T_DIM + 1];
    __shared__ float rpre[T_DIM + 1];

    // ---- label scan / compaction ----
    int p0 = tid * 4;
    int4 lv = *(const int4*)(labels + b * T_DIM + p0);
    int f0 = (lv.x == 1), f1 = (lv.y == 1), f2 = (lv.z == 1), f3 = (lv.w == 1);
    int cnt = f0 + f1 + f2 + f3;

    int incl = cnt;
    #pragma unroll
    for (int off = 1; off < 64; off <<= 1) {
        int n = __shfl_up(incl, off);
        if (lane >= off) incl += n;
    }
    if (lane == 63) waveTot[wave] = incl;
    __syncthreads();

    int waveOff = 0;
    for (int w = 0; w < wave; ++w) waveOff += waveTot[w];
    int t = waveTot[0] + waveTot[1] + waveTot[2] + waveTot[3];
    int r = waveOff + incl - cnt;

    if (f0) pos[r++] = p0 + 0;
    if (f1) pos[r++] = p0 + 1;
    if (f2) pos[r++] = p0 + 2;
    if (f3) pos[r++] = p0 + 3;
    __syncthreads();

    // ---- means of labeled rows, 2 rows per wave-iteration ----
    for (int rr = wave; rr < t; rr += 8) {
        const float* srcA = video + (size_t)pos[rr] * (B_DIM * C_DIM) + b * C_DIM;
        int rr2 = rr + 4;
        bool has2 = rr2 < t;
        const float* srcB = has2 ? video + (size_t)pos[rr2] * (B_DIM * C_DIM) + b * C_DIM
                                 : srcA;
        float4 va0 = *(const float4*)(srcA + lane * 4);
        float4 va1 = *(const float4*)(srcA + 256 + lane * 4);
        float4 vb0 = *(const float4*)(srcB + lane * 4);
        float4 vb1 = *(const float4*)(srcB + 256 + lane * 4);
        float sA = va0.x + va0.y + va0.z + va0.w + va1.x + va1.y + va1.z + va1.w;
        float sB = vb0.x + vb0.y + vb0.z + vb0.w + vb1.x + vb1.y + vb1.z + vb1.w;
        #pragma unroll
        for (int off = 32; off; off >>= 1) {
            sA += __shfl_xor(sA, off);
            sB += __shfl_xor(sB, off);
        }
        if (lane == 0) {
            vm[rr] = sA * (1.0f / C_DIM);
            if (has2) vm[rr2] = sB * (1.0f / C_DIM);
        }
    }
    __syncthreads();

    // ---- wave 0: prefix products pre[k] = vm[0]*..*vm[k-1], + reciprocals ----
    if (wave == 0) {
        float carry = 1.0f;
        for (int base = 0; base < t; base += 64) {
            int k = base + lane;
            float v = (k < t) ? vm[k] : 1.0f;
            float sc = v;
            #pragma unroll
            for (int off = 1; off < 64; off <<= 1) {
                float n = __shfl_up(sc, off);
                if (lane >= off) sc *= n;
            }
            if (k < t) {
                float pk = carry * sc;
                pre[k + 1]  = pk;
                rpre[k + 1] = 1.0f / pk;
            }
            carry *= __shfl(sc, 63);
        }
        if (lane == 0) { pre[0] = 1.0f; rpre[0] = 1.0f; }
    }
    __syncthreads();

    // ---- O(1) windowed product per position ----
    #pragma unroll
    for (int k = 0; k < 4; ++k) {
        int p  = p0 + k;
        int lo = p - (T_DIM - t); if (lo < 0) lo = 0;
        int hi = p < (t - 1) ? p : (t - 1);
        float s = (lo <= hi) ? pre[hi + 1] * rpre[lo] : 1.0f;
        scale_s[p * B_DIM + b] = s;
    }
}

// Kernel 2: pure stream. out[i] = audio[i] * scale_s[i>>7] (float4 units).
// Plain audio loads (keep L3-resident), nontemporal stores (out never read
// again — don't evict audio from L3).
__global__ __launch_bounds__(256) void k_apply(const float* __restrict__ audio,
                                               const float* __restrict__ scale_s,
                                               float* __restrict__ out) {
    int i0 = blockIdx.x * 256 + threadIdx.x;
    const int stride = 2048 * 256;
    const f32x4* ain = (const f32x4*)audio;
    f32x4* aout = (f32x4*)out;
    #pragma unroll
    for (int it = 0; it < 8; ++it) {
        int i = i0 + it * stride;
        float s  = scale_s[i >> 7];          // broadcast, L2-resident 128 KB
        f32x4 a  = ain[i];
        f32x4 o  = a * s;
        __builtin_nontemporal_store(o, aout + i);
    }
}

extern "C" void kernel_launch(void* const* d_in, const int* in_sizes, int n_in,
                              void* d_out, int out_size, void* d_ws, size_t ws_size,
                              hipStream_t stream) {
    const float* video  = (const float*)d_in[0];
    const float* audio  = (const float*)d_in[1];
    const int*   labels = (const int*)d_in[2];
    float* out     = (float*)d_out;
    float* scale_s = (float*)d_ws;           // T*B floats = 128 KB

    k_scale<<<B_DIM, 256, 0, stream>>>(video, labels, scale_s);
    k_apply<<<2048, 256, 0, stream>>>(audio, scale_s, out);
}

// Round 9
// 30.507 us; speedup vs baseline: 1.1882x; 1.1882x over previous
//
#include <hip/hip_runtime.h>

#define T_DIM 1024
#define B_DIM 32
#define C_DIM 512
#define PROWS 16   // p-rows per block

typedef float f32x4 __attribute__((ext_vector_type(4)));

// One block = one batch b, 16 consecutive p-rows.
//   A: labels + block-scan compaction of labeled positions
//   B: means of labeled rows — 4 rows per wave per round (1 round for t<=16)
//   C: wave0 prefix products pre[]/rpre[] (O(1) window lookup for all threads)
//   D: stream out[p,b,:] = audio[p,b,:] * scale
__global__ __launch_bounds__(256) void k_fused(const float* __restrict__ video,
                                               const float* __restrict__ audio,
                                               const int* __restrict__ labels,
                                               float* __restrict__ out) {
    int b     = blockIdx.y;
    int pBase = blockIdx.x * PROWS;
    int tid   = threadIdx.x;
    int lane  = tid & 63;
    int wave  = tid >> 6;
    __shared__ float vm[T_DIM];
    __shared__ int   pos[T_DIM];
    __shared__ int   waveTot[4];
    __shared__ float pre[T_DIM + 1];
    __shared__ float rpre[T_DIM + 1];

    // ---- phase A: labels + block scan ----
    int p0 = tid * 4;
    int4 lv = *(const int4*)(labels + b * T_DIM + p0);
    int f0 = (lv.x == 1), f1 = (lv.y == 1), f2 = (lv.z == 1), f3 = (lv.w == 1);
    int cnt = f0 + f1 + f2 + f3;

    int incl = cnt;
    #pragma unroll
    for (int off = 1; off < 64; off <<= 1) {
        int n = __shfl_up(incl, off);
        if (lane >= off) incl += n;
    }
    if (lane == 63) waveTot[wave] = incl;
    __syncthreads();

    int waveOff = 0;
    for (int w = 0; w < wave; ++w) waveOff += waveTot[w];
    int t = waveTot[0] + waveTot[1] + waveTot[2] + waveTot[3];
    int r = waveOff + incl - cnt;

    if (f0) pos[r++] = p0 + 0;
    if (f1) pos[r++] = p0 + 1;
    if (f2) pos[r++] = p0 + 2;
    if (f3) pos[r++] = p0 + 3;
    __syncthreads();

    // ---- phase B: means, 4 rows per wave per round ----
    for (int base = 0; base < t; base += 16) {
        int rr0 = base + wave;
        int rr1 = rr0 + 4, rr2 = rr0 + 8, rr3 = rr0 + 12;
        int rc0 = rr0 < t ? rr0 : 0;
        int rc1 = rr1 < t ? rr1 : 0;
        int rc2 = rr2 < t ? rr2 : 0;
        int rc3 = rr3 < t ? rr3 : 0;
        const float* s0p = video + (size_t)pos[rc0] * (B_DIM * C_DIM) + b * C_DIM;
        const float* s1p = video + (size_t)pos[rc1] * (B_DIM * C_DIM) + b * C_DIM;
        const float* s2p = video + (size_t)pos[rc2] * (B_DIM * C_DIM) + b * C_DIM;
        const float* s3p = video + (size_t)pos[rc3] * (B_DIM * C_DIM) + b * C_DIM;
        float4 x0a = *(const float4*)(s0p + lane * 4);
        float4 x0b = *(const float4*)(s0p + 256 + lane * 4);
        float4 x1a = *(const float4*)(s1p + lane * 4);
        float4 x1b = *(const float4*)(s1p + 256 + lane * 4);
        float4 x2a = *(const float4*)(s2p + lane * 4);
        float4 x2b = *(const float4*)(s2p + 256 + lane * 4);
        float4 x3a = *(const float4*)(s3p + lane * 4);
        float4 x3b = *(const float4*)(s3p + 256 + lane * 4);
        float v0 = x0a.x + x0a.y + x0a.z + x0a.w + x0b.x + x0b.y + x0b.z + x0b.w;
        float v1 = x1a.x + x1a.y + x1a.z + x1a.w + x1b.x + x1b.y + x1b.z + x1b.w;
        float v2 = x2a.x + x2a.y + x2a.z + x2a.w + x2b.x + x2b.y + x2b.z + x2b.w;
        float v3 = x3a.x + x3a.y + x3a.z + x3a.w + x3b.x + x3b.y + x3b.z + x3b.w;
        #pragma unroll
        for (int off = 32; off; off >>= 1) {
            v0 += __shfl_xor(v0, off);
            v1 += __shfl_xor(v1, off);
            v2 += __shfl_xor(v2, off);
            v3 += __shfl_xor(v3, off);
        }
        if (lane == 0) {
            if (rr0 < t) vm[rr0] = v0 * (1.0f / C_DIM);
            if (rr1 < t) vm[rr1] = v1 * (1.0f / C_DIM);
            if (rr2 < t) vm[rr2] = v2 * (1.0f / C_DIM);
            if (rr3 < t) vm[rr3] = v3 * (1.0f / C_DIM);
        }
    }
    __syncthreads();

    // ---- phase C: wave0 prefix products + reciprocals ----
    if (wave == 0) {
        float carry = 1.0f;
        for (int base = 0; base < t; base += 64) {
            int k = base + lane;
            float v = (k < t) ? vm[k] : 1.0f;
            float sc = v;
            #pragma unroll
            for (int off = 1; off < 64; off <<= 1) {
                float n = __shfl_up(sc, off);
                if (lane >= off) sc *= n;
            }
            if (k < t) {
                float pk = carry * sc;
                pre[k + 1]  = pk;
                rpre[k + 1] = 1.0f / pk;
            }
            carry *= __shfl(sc, 63);
        }
        if (lane == 0) { pre[0] = 1.0f; rpre[0] = 1.0f; }
    }
    __syncthreads();

    // ---- phase D: stream. thread handles rows k = 2*i + half ----
    int half = tid >> 7;
    int c4   = tid & 127;
    const int rstep = 2 * B_DIM * (C_DIM / 4);   // float4 units between rows
    int base0 = ((pBase + half) * B_DIM + b) * (C_DIM / 4) + c4;
    const f32x4* ain  = (const f32x4*)audio;
    f32x4*       aout = (f32x4*)out;

    float sc[8];
    #pragma unroll
    for (int i = 0; i < 8; ++i) {
        int p  = pBase + 2 * i + half;
        int lo = p - (T_DIM - t); if (lo < 0) lo = 0;
        int hi = p < (t - 1) ? p : (t - 1);
        sc[i] = (lo <= hi) ? pre[hi + 1] * rpre[lo] : 1.0f;
    }

    f32x4 a[8];
    #pragma unroll
    for (int i = 0; i < 8; ++i)
        a[i] = ain[base0 + i * rstep];
    #pragma unroll
    for (int i = 0; i < 8; ++i)
        aout[base0 + i * rstep] = a[i] * sc[i];
}

extern "C" void kernel_launch(void* const* d_in, const int* in_sizes, int n_in,
                              void* d_out, int out_size, void* d_ws, size_t ws_size,
                              hipStream_t stream) {
    const float* video  = (const float*)d_in[0];
    const float* audio  = (const float*)d_in[1];
    const int*   labels = (const int*)d_in[2];
    float* out = (float*)d_out;

    dim3 grid(T_DIM / PROWS, B_DIM);
    k_fused<<<grid, 256, 0, stream>>>(video, audio, labels, out);
}

// Round 10
// 29.751 us; speedup vs baseline: 1.2183x; 1.0254x over previous
//
#include <hip/hip_runtime.h>

#define T_DIM 1024
#define B_DIM 32
#define C_DIM 512
#define PROWS 16   // p-rows per block

typedef float f32x4 __attribute__((ext_vector_type(4)));

// R6 skeleton (best known), single change: nontemporal stores for out.
//   A: labels + block-scan compaction
//   B: means of labeled video rows (2 rows per wave-iteration)
//   C: issue remaining audio rows; 16-thread serial windowed product
//   D: mul + NT store burst
__global__ __launch_bounds__(256) void k_fused(const float* __restrict__ video,
                                               const float* __restrict__ audio,
                                               const int* __restrict__ labels,
                                               float* __restrict__ out) {
    int b     = blockIdx.y;
    int pBase = blockIdx.x * PROWS;
    int tid   = threadIdx.x;
    int lane  = tid & 63;
    int wave  = tid >> 6;
    __shared__ float vm[T_DIM];
    __shared__ int   pos[T_DIM];
    __shared__ int   waveTot[4];
    __shared__ float sscale[PROWS];

    // streaming geometry: thread handles rows k = 2*i + half, i = 0..7
    int half = tid >> 7;
    int c4   = tid & 127;
    const int rstep = 2 * B_DIM * (C_DIM / 4);
    int base0 = ((pBase + half) * B_DIM + b) * (C_DIM / 4) + c4;
    const f32x4* ain  = (const f32x4*)audio;
    f32x4*       aout = (f32x4*)out;

    // ---- phase A: prefetch first 2 audio rows + labels together ----
    f32x4 a0 = ain[base0];
    f32x4 a1 = ain[base0 + rstep];
    int4 lv = *(const int4*)(labels + b * T_DIM + tid * 4);

    int p0 = tid * 4;
    int f0 = (lv.x == 1), f1 = (lv.y == 1), f2 = (lv.z == 1), f3 = (lv.w == 1);
    int cnt = f0 + f1 + f2 + f3;

    int incl = cnt;
    #pragma unroll
    for (int off = 1; off < 64; off <<= 1) {
        int n = __shfl_up(incl, off);
        if (lane >= off) incl += n;
    }
    if (lane == 63) waveTot[wave] = incl;
    __syncthreads();

    int waveOff = 0;
    for (int w = 0; w < wave; ++w) waveOff += waveTot[w];
    int t = waveTot[0] + waveTot[1] + waveTot[2] + waveTot[3];
    int r = waveOff + incl - cnt;

    if (f0) pos[r++] = p0 + 0;
    if (f1) pos[r++] = p0 + 1;
    if (f2) pos[r++] = p0 + 2;
    if (f3) pos[r++] = p0 + 3;
    __syncthreads();

    // ---- phase B: means of labeled rows, 2 rows per wave-iteration ----
    for (int rr = wave; rr < t; rr += 8) {
        const float* srcA = video + (size_t)pos[rr] * (B_DIM * C_DIM) + b * C_DIM;
        int rr2 = rr + 4;
        bool has2 = rr2 < t;
        const float* srcB = has2 ? video + (size_t)pos[rr2] * (B_DIM * C_DIM) + b * C_DIM
                                 : srcA;
        float4 va0 = *(const float4*)(srcA + lane * 4);
        float4 va1 = *(const float4*)(srcA + 256 + lane * 4);
        float4 vb0 = *(const float4*)(srcB + lane * 4);
        float4 vb1 = *(const float4*)(srcB + 256 + lane * 4);
        float sA = va0.x + va0.y + va0.z + va0.w + va1.x + va1.y + va1.z + va1.w;
        float sB = vb0.x + vb0.y + vb0.z + vb0.w + vb1.x + vb1.y + vb1.z + vb1.w;
        #pragma unroll
        for (int off = 32; off; off >>= 1) {
            sA += __shfl_xor(sA, off);
            sB += __shfl_xor(sB, off);
        }
        if (lane == 0) {
            vm[rr] = sA * (1.0f / C_DIM);
            if (has2) vm[rr2] = sB * (1.0f / C_DIM);
        }
    }
    __syncthreads();

    // ---- phase C: issue remaining 6 audio rows, then windowed product ----
    f32x4 a2 = ain[base0 + 2 * rstep];
    f32x4 a3 = ain[base0 + 3 * rstep];
    f32x4 a4 = ain[base0 + 4 * rstep];
    f32x4 a5 = ain[base0 + 5 * rstep];
    f32x4 a6 = ain[base0 + 6 * rstep];
    f32x4 a7 = ain[base0 + 7 * rstep];

    if (tid < PROWS) {
        int p  = pBase + tid;
        int lo = p - (T_DIM - t); if (lo < 0) lo = 0;
        int hi = p < (t - 1) ? p : (t - 1);
        float s = 1.0f;
        for (int m = lo; m <= hi; ++m) s *= vm[m];
        sscale[tid] = s;
    }
    __syncthreads();

    // ---- phase D: mul + NT store burst ----
    float s0 = sscale[0 + half],  s1 = sscale[2 + half];
    float s2 = sscale[4 + half],  s3 = sscale[6 + half];
    float s4 = sscale[8 + half],  s5 = sscale[10 + half];
    float s6 = sscale[12 + half], s7 = sscale[14 + half];

    __builtin_nontemporal_store(a0 * s0, aout + base0 + 0 * rstep);
    __builtin_nontemporal_store(a1 * s1, aout + base0 + 1 * rstep);
    __builtin_nontemporal_store(a2 * s2, aout + base0 + 2 * rstep);
    __builtin_nontemporal_store(a3 * s3, aout + base0 + 3 * rstep);
    __builtin_nontemporal_store(a4 * s4, aout + base0 + 4 * rstep);
    __builtin_nontemporal_store(a5 * s5, aout + base0 + 5 * rstep);
    __builtin_nontemporal_store(a6 * s6, aout + base0 + 6 * rstep);
    __builtin_nontemporal_store(a7 * s7, aout + base0 + 7 * rstep);
}

extern "C" void kernel_launch(void* const* d_in, const int* in_sizes, int n_in,
                              void* d_out, int out_size, void* d_ws, size_t ws_size,
                              hipStream_t stream) {
    const float* video  = (const float*)d_in[0];
    const float* audio  = (const float*)d_in[1];
    const int*   labels = (const int*)d_in[2];
    float* out = (float*)d_out;

    dim3 grid(T_DIM / PROWS, B_DIM);
    k_fused<<<grid, 256, 0, stream>>>(video, audio, labels, out);
}

// Round 11
// 28.395 us; speedup vs baseline: 1.2765x; 1.0478x over previous
//
#include <hip/hip_runtime.h>

#define T_DIM 1024
#define B_DIM 32
#define C_DIM 512
#define PROWS 32   // p-rows per block (A/B vs R6's 16)

typedef float f32x4 __attribute__((ext_vector_type(4)));

// R6 skeleton, PROWS=32: one block = one batch b, 32 consecutive p-rows.
//   A: prefetch first 2 audio rows + labels; block-scan compaction
//   B: means of labeled video rows (2 rows per wave-iteration)
//   C: issue remaining 14 audio rows; 32-thread serial windowed product
//   D: mul + store burst
__global__ __launch_bounds__(256) void k_fused(const float* __restrict__ video,
                                               const float* __restrict__ audio,
                                               const int* __restrict__ labels,
                                               float* __restrict__ out) {
    int b     = blockIdx.y;
    int pBase = blockIdx.x * PROWS;
    int tid   = threadIdx.x;
    int lane  = tid & 63;
    int wave  = tid >> 6;
    __shared__ float vm[T_DIM];
    __shared__ int   pos[T_DIM];
    __shared__ int   waveTot[4];
    __shared__ float sscale[PROWS];

    // streaming geometry: thread handles rows k = 2*i + half, i = 0..15
    int half = tid >> 7;
    int c4   = tid & 127;
    const int rstep = 2 * B_DIM * (C_DIM / 4);
    int base0 = ((pBase + half) * B_DIM + b) * (C_DIM / 4) + c4;
    const f32x4* ain  = (const f32x4*)audio;
    f32x4*       aout = (f32x4*)out;

    // ---- phase A: prefetch first 2 audio rows + labels together ----
    f32x4 a0 = ain[base0];
    f32x4 a1 = ain[base0 + rstep];
    int4 lv = *(const int4*)(labels + b * T_DIM + tid * 4);

    int p0 = tid * 4;
    int f0 = (lv.x == 1), f1 = (lv.y == 1), f2 = (lv.z == 1), f3 = (lv.w == 1);
    int cnt = f0 + f1 + f2 + f3;

    int incl = cnt;
    #pragma unroll
    for (int off = 1; off < 64; off <<= 1) {
        int n = __shfl_up(incl, off);
        if (lane >= off) incl += n;
    }
    if (lane == 63) waveTot[wave] = incl;
    __syncthreads();

    int waveOff = 0;
    for (int w = 0; w < wave; ++w) waveOff += waveTot[w];
    int t = waveTot[0] + waveTot[1] + waveTot[2] + waveTot[3];
    int r = waveOff + incl - cnt;

    if (f0) pos[r++] = p0 + 0;
    if (f1) pos[r++] = p0 + 1;
    if (f2) pos[r++] = p0 + 2;
    if (f3) pos[r++] = p0 + 3;
    __syncthreads();

    // ---- phase B: means of labeled rows, 2 rows per wave-iteration ----
    for (int rr = wave; rr < t; rr += 8) {
        const float* srcA = video + (size_t)pos[rr] * (B_DIM * C_DIM) + b * C_DIM;
        int rr2 = rr + 4;
        bool has2 = rr2 < t;
        const float* srcB = has2 ? video + (size_t)pos[rr2] * (B_DIM * C_DIM) + b * C_DIM
                                 : srcA;
        float4 va0 = *(const float4*)(srcA + lane * 4);
        float4 va1 = *(const float4*)(srcA + 256 + lane * 4);
        float4 vb0 = *(const float4*)(srcB + lane * 4);
        float4 vb1 = *(const float4*)(srcB + 256 + lane * 4);
        float sA = va0.x + va0.y + va0.z + va0.w + va1.x + va1.y + va1.z + va1.w;
        float sB = vb0.x + vb0.y + vb0.z + vb0.w + vb1.x + vb1.y + vb1.z + vb1.w;
        #pragma unroll
        for (int off = 32; off; off >>= 1) {
            sA += __shfl_xor(sA, off);
            sB += __shfl_xor(sB, off);
        }
        if (lane == 0) {
            vm[rr] = sA * (1.0f / C_DIM);
            if (has2) vm[rr2] = sB * (1.0f / C_DIM);
        }
    }
    __syncthreads();

    // ---- phase C: issue remaining 14 audio rows, then windowed product ----
    f32x4 a2  = ain[base0 +  2 * rstep];
    f32x4 a3  = ain[base0 +  3 * rstep];
    f32x4 a4  = ain[base0 +  4 * rstep];
    f32x4 a5  = ain[base0 +  5 * rstep];
    f32x4 a6  = ain[base0 +  6 * rstep];
    f32x4 a7  = ain[base0 +  7 * rstep];
    f32x4 a8  = ain[base0 +  8 * rstep];
    f32x4 a9  = ain[base0 +  9 * rstep];
    f32x4 a10 = ain[base0 + 10 * rstep];
    f32x4 a11 = ain[base0 + 11 * rstep];
    f32x4 a12 = ain[base0 + 12 * rstep];
    f32x4 a13 = ain[base0 + 13 * rstep];
    f32x4 a14 = ain[base0 + 14 * rstep];
    f32x4 a15 = ain[base0 + 15 * rstep];

    if (tid < PROWS) {
        int p  = pBase + tid;
        int lo = p - (T_DIM - t); if (lo < 0) lo = 0;
        int hi = p < (t - 1) ? p : (t - 1);
        float s = 1.0f;
        for (int m = lo; m <= hi; ++m) s *= vm[m];
        sscale[tid] = s;
    }
    __syncthreads();

    // ---- phase D: mul + store burst ----
    float s0  = sscale[ 0 + half], s1  = sscale[ 2 + half];
    float s2  = sscale[ 4 + half], s3  = sscale[ 6 + half];
    float s4  = sscale[ 8 + half], s5  = sscale[10 + half];
    float s6  = sscale[12 + half], s7  = sscale[14 + half];
    float s8  = sscale[16 + half], s9  = sscale[18 + half];
    float s10 = sscale[20 + half], s11 = sscale[22 + half];
    float s12 = sscale[24 + half], s13 = sscale[26 + half];
    float s14 = sscale[28 + half], s15 = sscale[30 + half];

    aout[base0 +  0 * rstep] = a0  * s0;
    aout[base0 +  1 * rstep] = a1  * s1;
    aout[base0 +  2 * rstep] = a2  * s2;
    aout[base0 +  3 * rstep] = a3  * s3;
    aout[base0 +  4 * rstep] = a4  * s4;
    aout[base0 +  5 * rstep] = a5  * s5;
    aout[base0 +  6 * rstep] = a6  * s6;
    aout[base0 +  7 * rstep] = a7  * s7;
    aout[base0 +  8 * rstep] = a8  * s8;
    aout[base0 +  9 * rstep] = a9  * s9;
    aout[base0 + 10 * rstep] = a10 * s10;
    aout[base0 + 11 * rstep] = a11 * s11;
    aout[base0 + 12 * rstep] = a12 * s12;
    aout[base0 + 13 * rstep] = a13 * s13;
    aout[base0 + 14 * rstep] = a14 * s14;
    aout[base0 + 15 * rstep] = a15 * s15;
}

extern "C" void kernel_launch(void* const* d_in, const int* in_sizes, int n_in,
                              void* d_out, int out_size, void* d_ws, size_t ws_size,
                              hipStream_t stream) {
    const float* video  = (const float*)d_in[0];
    const float* audio  = (const float*)d_in[1];
    const int*   labels = (const int*)d_in[2];
    float* out = (float*)d_out;

    dim3 grid(T_DIM / PROWS, B_DIM);
    k_fused<<<grid, 256, 0, stream>>>(video, audio, labels, out);
}

// Round 12
// 26.989 us; speedup vs baseline: 1.3430x; 1.0521x over previous
//
#include <hip/hip_runtime.h>

#define T_DIM 1024
#define B_DIM 32
#define C_DIM 512
#define PROWS 64   // p-rows per block (A/B: 16->29.2us, 32->28.4us, now 64)

typedef float f32x4 __attribute__((ext_vector_type(4)));

// R6/R11 skeleton, PROWS=64: one block = one batch b, 64 consecutive p-rows.
//   A: prefetch first 2 audio rows + labels; block-scan compaction
//   B: means of labeled video rows (2 rows per wave-iteration)
//   C: issue remaining 30 audio rows; 64-thread serial windowed product
//   D: mul + store burst
__global__ __launch_bounds__(256) void k_fused(const float* __restrict__ video,
                                               const float* __restrict__ audio,
                                               const int* __restrict__ labels,
                                               float* __restrict__ out) {
    int b     = blockIdx.y;
    int pBase = blockIdx.x * PROWS;
    int tid   = threadIdx.x;
    int lane  = tid & 63;
    int wave  = tid >> 6;
    __shared__ float vm[T_DIM];
    __shared__ int   pos[T_DIM];
    __shared__ int   waveTot[4];
    __shared__ float sscale[PROWS];

    // streaming geometry: thread handles rows k = 2*i + half, i = 0..31
    int half = tid >> 7;
    int c4   = tid & 127;
    const int rstep = 2 * B_DIM * (C_DIM / 4);
    int base0 = ((pBase + half) * B_DIM + b) * (C_DIM / 4) + c4;
    const f32x4* ain  = (const f32x4*)audio;
    f32x4*       aout = (f32x4*)out;

    // ---- phase A: prefetch first 2 audio rows + labels together ----
    f32x4 a[32];
    a[0] = ain[base0];
    a[1] = ain[base0 + rstep];
    int4 lv = *(const int4*)(labels + b * T_DIM + tid * 4);

    int p0 = tid * 4;
    int f0 = (lv.x == 1), f1 = (lv.y == 1), f2 = (lv.z == 1), f3 = (lv.w == 1);
    int cnt = f0 + f1 + f2 + f3;

    int incl = cnt;
    #pragma unroll
    for (int off = 1; off < 64; off <<= 1) {
        int n = __shfl_up(incl, off);
        if (lane >= off) incl += n;
    }
    if (lane == 63) waveTot[wave] = incl;
    __syncthreads();

    int waveOff = 0;
    for (int w = 0; w < wave; ++w) waveOff += waveTot[w];
    int t = waveTot[0] + waveTot[1] + waveTot[2] + waveTot[3];
    int r = waveOff + incl - cnt;

    if (f0) pos[r++] = p0 + 0;
    if (f1) pos[r++] = p0 + 1;
    if (f2) pos[r++] = p0 + 2;
    if (f3) pos[r++] = p0 + 3;
    __syncthreads();

    // ---- phase B: means of labeled rows, 2 rows per wave-iteration ----
    for (int rr = wave; rr < t; rr += 8) {
        const float* srcA = video + (size_t)pos[rr] * (B_DIM * C_DIM) + b * C_DIM;
        int rr2 = rr + 4;
        bool has2 = rr2 < t;
        const float* srcB = has2 ? video + (size_t)pos[rr2] * (B_DIM * C_DIM) + b * C_DIM
                                 : srcA;
        float4 va0 = *(const float4*)(srcA + lane * 4);
        float4 va1 = *(const float4*)(srcA + 256 + lane * 4);
        float4 vb0 = *(const float4*)(srcB + lane * 4);
        float4 vb1 = *(const float4*)(srcB + 256 + lane * 4);
        float sA = va0.x + va0.y + va0.z + va0.w + va1.x + va1.y + va1.z + va1.w;
        float sB = vb0.x + vb0.y + vb0.z + vb0.w + vb1.x + vb1.y + vb1.z + vb1.w;
        #pragma unroll
        for (int off = 32; off; off >>= 1) {
            sA += __shfl_xor(sA, off);
            sB += __shfl_xor(sB, off);
        }
        if (lane == 0) {
            vm[rr] = sA * (1.0f / C_DIM);
            if (has2) vm[rr2] = sB * (1.0f / C_DIM);
        }
    }
    __syncthreads();

    // ---- phase C: issue remaining 30 audio rows, then windowed product ----
    #pragma unroll
    for (int i = 2; i < 32; ++i)
        a[i] = ain[base0 + i * rstep];

    if (tid < PROWS) {
        int p  = pBase + tid;
        int lo = p - (T_DIM - t); if (lo < 0) lo = 0;
        int hi = p < (t - 1) ? p : (t - 1);
        float s = 1.0f;
        for (int m = lo; m <= hi; ++m) s *= vm[m];
        sscale[tid] = s;
    }
    __syncthreads();

    // ---- phase D: mul + store burst ----
    #pragma unroll
    for (int i = 0; i < 32; ++i) {
        float s = sscale[2 * i + half];
        aout[base0 + i * rstep] = a[i] * s;
    }
}

extern "C" void kernel_launch(void* const* d_in, const int* in_sizes, int n_in,
                              void* d_out, int out_size, void* d_ws, size_t ws_size,
                              hipStream_t stream) {
    const float* video  = (const float*)d_in[0];
    const float* audio  = (const float*)d_in[1];
    const int*   labels = (const int*)d_in[2];
    float* out = (float*)d_out;

    dim3 grid(T_DIM / PROWS, B_DIM);
    k_fused<<<grid, 256, 0, stream>>>(video, audio, labels, out);
}